// Round 2
// baseline (853.433 us; speedup 1.0000x reference)
//
#include <hip/hip_runtime.h>
#include <math.h>

// ---------------- GEMM (fp32 vector, LDS tiled) ----------------
// C[M x Nc] = act(A[M x K] @ B[K x Nc] + bias), A either direct or the
// virtual "combined" = [x | memory | h] concat (K=384).
// MODE 0: xt = x@W              (A=Adir, no bias/act)
// MODE 1: u1 = relu(comb@Wu1+b) (A=combined)
// MODE 2: t2 = u1@Wu2+b         (A=Adir)
// MODE 3: um = g*mem+(1-g)*tanh(comb@Wn+b), g=sigmoid(t2)  (A=combined)
#define BM 64
#define BN 128
#define BK 32
#define TM 4
#define TN 8

template<int MODE>
__global__ __launch_bounds__(256)
void gemm_kernel(const float* __restrict__ Xp, const float* __restrict__ Mem,
                 const float* __restrict__ Hh, const float* __restrict__ Adir,
                 const float* __restrict__ B, const float* __restrict__ bias,
                 const float* __restrict__ T2, float* __restrict__ C,
                 int M, int Nc, int K)
{
    __shared__ float AsT[BK][BM + 4];
    __shared__ float Bs[BK][BN + 4];
    const int row0 = blockIdx.x * BM;
    const int col0 = blockIdx.y * BN;
    const int tid = threadIdx.x;
    const int tr = tid >> 4, tc = tid & 15;

    float acc[TM][TN];
#pragma unroll
    for (int m = 0; m < TM; ++m)
#pragma unroll
        for (int n = 0; n < TN; ++n) acc[m][n] = 0.f;

    for (int k0 = 0; k0 < K; k0 += BK) {
        // ---- load A tile (64x32), 8 floats/thread, store transposed ----
        {
            const int arow = tid >> 2;
            const int acol = (tid & 3) * 8;
            const int gr = row0 + arow;
            float v[8];
            if (gr < M) {
#pragma unroll
                for (int j = 0; j < 8; j += 4) {
                    const int gk = k0 + acol + j;
                    const float* sp;
                    if (MODE == 1 || MODE == 3) {
                        const float* base = (gk < 128) ? Xp : ((gk < 256) ? Mem : Hh);
                        sp = base + (size_t)gr * 128 + (gk & 127);
                    } else {
                        sp = Adir + (size_t)gr * K + gk;
                    }
                    const float4 t = *(const float4*)sp;
                    v[j] = t.x; v[j + 1] = t.y; v[j + 2] = t.z; v[j + 3] = t.w;
                }
            } else {
#pragma unroll
                for (int j = 0; j < 8; ++j) v[j] = 0.f;
            }
#pragma unroll
            for (int j = 0; j < 8; ++j) AsT[acol + j][arow] = v[j];
        }
        // ---- load B tile (32x128), 4 float4/thread ----
        {
#pragma unroll
            for (int j = 0; j < 4; ++j) {
                const int idx = tid + j * 256;
                const int bk = idx >> 5;
                const int bc = (idx & 31) * 4;
                const float4 t = *(const float4*)(B + (size_t)(k0 + bk) * Nc + col0 + bc);
                *(float4*)&Bs[bk][bc] = t;
            }
        }
        __syncthreads();
#pragma unroll
        for (int kk = 0; kk < BK; ++kk) {
            const float4 a4 = *(const float4*)&AsT[kk][tr * TM];
            const float4 b4a = *(const float4*)&Bs[kk][tc * TN];
            const float4 b4b = *(const float4*)&Bs[kk][tc * TN + 4];
            const float a[TM] = {a4.x, a4.y, a4.z, a4.w};
            const float b[TN] = {b4a.x, b4a.y, b4a.z, b4a.w, b4b.x, b4b.y, b4b.z, b4b.w};
#pragma unroll
            for (int m = 0; m < TM; ++m)
#pragma unroll
                for (int n = 0; n < TN; ++n)
                    acc[m][n] = fmaf(a[m], b[n], acc[m][n]);
        }
        __syncthreads();
    }
    // ---- epilogue ----
#pragma unroll
    for (int m = 0; m < TM; ++m) {
        const int gr = row0 + tr * TM + m;
        if (gr >= M) continue;
        const int gc0 = col0 + tc * TN;
#pragma unroll
        for (int half = 0; half < 2; ++half) {
            float vv[4];
#pragma unroll
            for (int q = 0; q < 4; ++q) {
                const int n = half * 4 + q;
                const int gc = gc0 + n;
                float val = acc[m][n];
                if (MODE == 1) { val += bias[gc]; val = val > 0.f ? val : 0.f; }
                else if (MODE == 2) { val += bias[gc]; }
                else if (MODE == 3) {
                    val = tanhf(val + bias[gc]);
                    const float t2v = T2[(size_t)gr * 128 + gc];
                    const float g = 1.f / (1.f + __expf(-t2v));
                    const float mm = Mem[(size_t)gr * 128 + gc];
                    val = g * mm + (1.f - g) * val;
                }
                vv[q] = val;
            }
            float4 o; o.x = vv[0]; o.y = vv[1]; o.z = vv[2]; o.w = vv[3];
            *(float4*)(C + (size_t)gr * Nc + gc0 + half * 4) = o;
        }
    }
}

// ---------------- attention scores: a_src[n,h], a_dst[n,h] ----------------
__global__ __launch_bounds__(256)
void attn_kernel(const float* __restrict__ xt, const float* __restrict__ att_s,
                 const float* __restrict__ att_d, float* __restrict__ a_src,
                 float* __restrict__ a_dst, int tot)
{
    const int t = blockIdx.x * blockDim.x + threadIdx.x;
    if (t >= tot) return;
    const int h = t & 7;
    const size_t n = (size_t)(t >> 3);
    const float* xp = xt + n * 128 + h * 16;
    const float* as = att_s + h * 16;
    const float* ad = att_d + h * 16;
    float s1 = 0.f, s2 = 0.f;
#pragma unroll
    for (int j = 0; j < 16; j += 4) {
        const float4 xv = *(const float4*)(xp + j);
        const float4 av = *(const float4*)(as + j);
        const float4 dv = *(const float4*)(ad + j);
        s1 += xv.x * av.x + xv.y * av.y + xv.z * av.z + xv.w * av.w;
        s2 += xv.x * dv.x + xv.y * dv.y + xv.z * dv.z + xv.w * dv.w;
    }
    a_src[t] = s1;
    a_dst[t] = s2;
}

// ---------------- edge pass: one wave per edge ----------------
// w = exp(leaky_relu(a_src[src]+a_dst[dst]))  (softmax shift skipped - invariant)
// z[dst,h]   += w
// agg[dst,c] += w[head(c)] * xt[src,c]
__global__ __launch_bounds__(256)
void edge_kernel(const int* __restrict__ ei, const float* __restrict__ a_src,
                 const float* __restrict__ a_dst, const float* __restrict__ xt,
                 float* __restrict__ agg, float* __restrict__ z, int Etot, int E)
{
    const int lane = threadIdx.x & 63;
    int wid = (int)((blockIdx.x * blockDim.x + threadIdx.x) >> 6);
    const int nw = (int)((gridDim.x * (size_t)blockDim.x) >> 6);
    for (int i = wid; i < Etot; i += nw) {
        int src, dst;
        if (i < E) { src = ei[i]; dst = ei[E + i]; }
        else { src = dst = i - E; }
        const int h = lane & 7;
        float eh = a_src[(size_t)src * 8 + h] + a_dst[(size_t)dst * 8 + h];
        eh = eh > 0.f ? eh : 0.2f * eh;
        const float w = __expf(eh);
        if (lane < 8) atomicAdd(&z[(size_t)dst * 8 + h], w);
        const float w0 = __shfl(w, lane >> 4);
        const float w1 = __shfl(w, (lane >> 4) + 4);
        const size_t sb = (size_t)src * 128, db = (size_t)dst * 128;
        atomicAdd(&agg[db + lane], xt[sb + lane] * w0);
        atomicAdd(&agg[db + 64 + lane], xt[sb + 64 + lane] * w1);
    }
}

// ---------------- normalize + bias + residual + LayerNorm ----------------
__global__ __launch_bounds__(256)
void norm_kernel(const float* __restrict__ agg, const float* __restrict__ z,
                 const float* __restrict__ x, const float* __restrict__ b_gat,
                 const float* __restrict__ ln_w, const float* __restrict__ ln_b,
                 float* __restrict__ hout, int Nn)
{
    const int lane = threadIdx.x & 63;
    int wid = (int)((blockIdx.x * blockDim.x + threadIdx.x) >> 6);
    const int nw = (int)((gridDim.x * (size_t)blockDim.x) >> 6);
    for (int n = wid; n < Nn; n += nw) {
        const size_t base = (size_t)n * 128;
        const float z0 = z[(size_t)n * 8 + (lane >> 4)];
        const float z1 = z[(size_t)n * 8 + 4 + (lane >> 4)];
        float v0 = agg[base + lane] / z0 + b_gat[lane] + x[base + lane];
        float v1 = agg[base + 64 + lane] / z1 + b_gat[64 + lane] + x[base + 64 + lane];
        float s = v0 + v1;
#pragma unroll
        for (int o = 32; o; o >>= 1) s += __shfl_xor(s, o);
        const float mu = s * (1.f / 128.f);
        const float d0 = v0 - mu, d1 = v1 - mu;
        float q = d0 * d0 + d1 * d1;
#pragma unroll
        for (int o = 32; o; o >>= 1) q += __shfl_xor(q, o);
        const float rs = rsqrtf(q * (1.f / 128.f) + 1e-5f);
        hout[base + lane] = d0 * rs * ln_w[lane] + ln_b[lane];
        hout[base + 64 + lane] = d1 * rs * ln_w[64 + lane] + ln_b[64 + lane];
    }
}

extern "C" void kernel_launch(void* const* d_in, const int* in_sizes, int n_in,
                              void* d_out, int out_size, void* d_ws, size_t ws_size,
                              hipStream_t stream)
{
    const float* x     = (const float*)d_in[0];
    const int*   ei    = (const int*)d_in[1];
    const float* mem   = (const float*)d_in[2];
    const float* W     = (const float*)d_in[3];
    const float* b_gat = (const float*)d_in[4];
    const float* att_s = (const float*)d_in[5];
    const float* att_d = (const float*)d_in[6];
    const float* ln_w  = (const float*)d_in[7];
    const float* ln_b  = (const float*)d_in[8];
    const float* Wu1   = (const float*)d_in[9];
    const float* bu1   = (const float*)d_in[10];
    const float* Wu2   = (const float*)d_in[11];
    const float* bu2   = (const float*)d_in[12];
    // d_in[13]=Wr, d_in[14]=br : reset gate is dead code in the reference
    const float* Wn    = (const float*)d_in[15];
    const float* bn    = (const float*)d_in[16];

    const int N = in_sizes[0] / 128;
    const int E = in_sizes[1] / 2;
    const int Etot = E + N;
    const size_t nd = (size_t)N * 128;

    float* ws    = (float*)d_ws;
    float* xt    = ws;                      // N*128
    float* agg   = ws + nd;                 // N*128
    float* a_src = ws + 2 * nd;             // N*8
    float* a_dst = a_src + (size_t)N * 8;   // N*8
    float* z     = a_dst + (size_t)N * 8;   // N*8
    float* t2    = z + (size_t)N * 8;       // N*128
    float* u1    = ws;                      // N*256, aliases xt+agg (dead by then)

    float* h_out  = (float*)d_out;          // N*128
    float* um_out = h_out + nd;             // N*128

    hipMemsetAsync(agg, 0, nd * sizeof(float), stream);
    hipMemsetAsync(z, 0, (size_t)N * 8 * sizeof(float), stream);

    const int mtiles = (N + BM - 1) / BM;

    // xt = x @ W
    gemm_kernel<0><<<dim3(mtiles, 1), 256, 0, stream>>>(
        nullptr, nullptr, nullptr, x, W, nullptr, nullptr, xt, N, 128, 128);

    // attention scores
    attn_kernel<<<(N * 8 + 255) / 256, 256, 0, stream>>>(xt, att_s, att_d, a_src, a_dst, N * 8);

    // edge aggregation
    {
        int nb = (Etot + 3) / 4;
        if (nb > 65535) nb = 65535;
        edge_kernel<<<nb, 256, 0, stream>>>(ei, a_src, a_dst, xt, agg, z, Etot, E);
    }

    // normalize + LN -> h
    norm_kernel<<<(N + 3) / 4, 256, 0, stream>>>(agg, z, x, b_gat, ln_w, ln_b, h_out, N);

    // u1 = relu(combined @ Wu1 + bu1)
    gemm_kernel<1><<<dim3(mtiles, 2), 256, 0, stream>>>(
        x, mem, h_out, nullptr, Wu1, bu1, nullptr, u1, N, 256, 384);

    // t2 = u1 @ Wu2 + bu2
    gemm_kernel<2><<<dim3(mtiles, 1), 256, 0, stream>>>(
        nullptr, nullptr, nullptr, u1, Wu2, bu2, nullptr, t2, N, 128, 256);

    // um = sigmoid(t2)*mem + (1-sigmoid(t2))*tanh(combined @ Wn + bn)
    gemm_kernel<3><<<dim3(mtiles, 1), 256, 0, stream>>>(
        x, mem, h_out, nullptr, Wn, bn, t2, um_out, N, 128, 384);
}

// Round 3
// 494.810 us; speedup vs baseline: 1.7248x; 1.7248x over previous
//
#include <hip/hip_runtime.h>
#include <math.h>

typedef unsigned short u16;
typedef short s8v __attribute__((ext_vector_type(8)));
typedef unsigned short us8 __attribute__((ext_vector_type(8)));
typedef unsigned short us4 __attribute__((ext_vector_type(4)));
typedef float f4v __attribute__((ext_vector_type(4)));

__device__ __forceinline__ u16 f2b(float f) {
    union { float f; unsigned u; } v; v.f = f;
    unsigned r = (v.u + 0x7FFFu + ((v.u >> 16) & 1u)) >> 16;
    return (u16)r;
}
__device__ __forceinline__ float b2f(u16 b) {
    union { unsigned u; float f; } v; v.u = ((unsigned)b) << 16;
    return v.f;
}

// ---------- convert x, memory to bf16 ----------
__global__ __launch_bounds__(256)
void conv_xmem(const float* __restrict__ x, const float* __restrict__ mem,
               u16* __restrict__ xb, u16* __restrict__ mb, int tot4)
{
    int t = blockIdx.x * 256 + threadIdx.x;
    if (t >= tot4) return;
    float4 vx = ((const float4*)x)[t];
    float4 vm = ((const float4*)mem)[t];
    us4 a, b;
    a[0] = f2b(vx.x); a[1] = f2b(vx.y); a[2] = f2b(vx.z); a[3] = f2b(vx.w);
    b[0] = f2b(vm.x); b[1] = f2b(vm.y); b[2] = f2b(vm.z); b[3] = f2b(vm.w);
    ((us4*)xb)[t] = a;
    ((us4*)mb)[t] = b;
}

// ---------- transpose + convert weights: Wt[c][k] = bf16(W[k][c]) ----------
__global__ __launch_bounds__(256)
void conv_w(const float* __restrict__ W, const float* __restrict__ Wu1,
            const float* __restrict__ Wu2, const float* __restrict__ Wn,
            u16* __restrict__ Wt, u16* __restrict__ Wu1t,
            u16* __restrict__ Wu2t, u16* __restrict__ Wnt)
{
    const int y = blockIdx.y;
    const int idx = blockIdx.x * 256 + threadIdx.x;
    const float* src; u16* dst; int K, Nc;
    if (y == 0)      { src = W;   dst = Wt;   K = 128; Nc = 128; }
    else if (y == 1) { src = Wu1; dst = Wu1t; K = 384; Nc = 256; }
    else if (y == 2) { src = Wu2; dst = Wu2t; K = 256; Nc = 128; }
    else             { src = Wn;  dst = Wnt;  K = 384; Nc = 128; }
    if (idx >= K * Nc) return;
    const int k = idx / Nc, c = idx % Nc;  // Nc is pow2 -> shifts
    dst[c * K + k] = f2b(src[idx]);
}

// ---------- bf16 MFMA GEMM ----------
// MODE 0: xt_bf = x_bf @ Wt           (K=128, Nc=128, out bf16)
// MODE 1: u1_bf = relu(comb @ Wu1t+b) (K=384, Nc=256, out bf16), comb=[x|mem|h] bf16
// MODE 2: t2_bf = u1_bf @ Wu2t + b    (K=256, Nc=128, out bf16)
// MODE 3: um = g*mem+(1-g)*tanh(comb@Wnt+b), g=sigmoid(t2) (K=384, Nc=128, out f32)
// Layout (m89/m91/m92-verified): a_frag = A[m=lane&15][k=(lane>>4)*8+j];
// b_frag = B[k][n=lane&15]; D reg q -> row=(lane>>4)*4+q, col=lane&15.
template<int MODE>
__global__ __launch_bounds__(256)
void mfma_gemm(const u16* __restrict__ Ad, const u16* __restrict__ Xb,
               const u16* __restrict__ Mb, const u16* __restrict__ Hb,
               const u16* __restrict__ Bt, const float* __restrict__ bias,
               const u16* __restrict__ T2b, const float* __restrict__ MemF,
               float* __restrict__ outF, u16* __restrict__ outB, int M)
{
    constexpr int K = (MODE == 0) ? 128 : ((MODE == 2) ? 256 : 384);
    __shared__ __align__(16) u16 As[64][40];   // +8 pad: 80B row stride
    __shared__ __align__(16) u16 Bs[128][40];
    const int tid = threadIdx.x;
    const int lane = tid & 63;
    const int wid = tid >> 6;
    const int wr = wid >> 1, wc = wid & 1;     // 2x2 waves -> 64x128 tile
    const int row0 = blockIdx.x * 64;
    const int col0 = blockIdx.y * 128;

    f4v acc[2][4];
#pragma unroll
    for (int a = 0; a < 2; ++a)
#pragma unroll
        for (int b = 0; b < 4; ++b)
#pragma unroll
            for (int q = 0; q < 4; ++q) acc[a][b][q] = 0.f;

    const int ar = tid >> 2;            // 0..63 (A row)
    const int akc = (tid & 3) * 8;      // k within 32-chunk
    const int bc = tid >> 1;            // 0..127 (B col)
    const int bko = (tid & 1) * 16;
    const int lr = lane & 15;
    const int kg = lane >> 4;

    for (int k0 = 0; k0 < K; k0 += 32) {
        // stage A tile 64x32
        {
            int gr = row0 + ar; if (gr > M - 1) gr = M - 1;
            const int gk = k0 + akc;
            const u16* src;
            if (MODE == 1 || MODE == 3) {
                const u16* base = (gk < 128) ? Xb : ((gk < 256) ? Mb : Hb);
                src = base + (size_t)gr * 128 + (gk & 127);
            } else {
                src = Ad + (size_t)gr * K + gk;
            }
            *(us8*)&As[ar][akc] = *(const us8*)src;
        }
        // stage B tile 32k x 128n from Bt[n][k] (k-contiguous)
        {
            const u16* src = Bt + (size_t)(col0 + bc) * K + k0 + bko;
            *(us8*)&Bs[bc][bko]     = ((const us8*)src)[0];
            *(us8*)&Bs[bc][bko + 8] = ((const us8*)src)[1];
        }
        __syncthreads();
        const s8v a0 = *(const s8v*)&As[wr * 32 + lr][kg * 8];
        const s8v a1 = *(const s8v*)&As[wr * 32 + 16 + lr][kg * 8];
#pragma unroll
        for (int ni = 0; ni < 4; ++ni) {
            const s8v b = *(const s8v*)&Bs[wc * 64 + ni * 16 + lr][kg * 8];
            acc[0][ni] = __builtin_amdgcn_mfma_f32_16x16x32_bf16(a0, b, acc[0][ni], 0, 0, 0);
            acc[1][ni] = __builtin_amdgcn_mfma_f32_16x16x32_bf16(a1, b, acc[1][ni], 0, 0, 0);
        }
        __syncthreads();
    }
#pragma unroll
    for (int mi = 0; mi < 2; ++mi) {
#pragma unroll
        for (int ni = 0; ni < 4; ++ni) {
#pragma unroll
            for (int q = 0; q < 4; ++q) {
                const int row = row0 + wr * 32 + mi * 16 + kg * 4 + q;
                const int col = col0 + wc * 64 + ni * 16 + lr;
                if (row >= M) continue;
                float v = acc[mi][ni][q];
                if (MODE == 0) {
                    outB[(size_t)row * 128 + col] = f2b(v);
                } else if (MODE == 1) {
                    v += bias[col]; v = v > 0.f ? v : 0.f;
                    outB[(size_t)row * 256 + col] = f2b(v);
                } else if (MODE == 2) {
                    v += bias[col];
                    outB[(size_t)row * 128 + col] = f2b(v);
                } else {
                    v = tanhf(v + bias[col]);
                    const float t2 = b2f(T2b[(size_t)row * 128 + col]);
                    const float g = 1.f / (1.f + __expf(-t2));
                    const float mm = MemF[(size_t)row * 128 + col];
                    outF[(size_t)row * 128 + col] = g * mm + (1.f - g) * v;
                }
            }
        }
    }
}

// ---------- attention scores ----------
__global__ __launch_bounds__(256)
void attn_kernel(const u16* __restrict__ xt, const float* __restrict__ as_,
                 const float* __restrict__ ad_, float* __restrict__ a_src,
                 float* __restrict__ a_dst, int tot)
{
    const int t = blockIdx.x * 256 + threadIdx.x;
    if (t >= tot) return;
    const int h = t & 7;
    const size_t n = (size_t)(t >> 3);
    const u16* xp = xt + n * 128 + h * 16;
    const us8 v0 = ((const us8*)xp)[0], v1 = ((const us8*)xp)[1];
    float s1 = 0.f, s2 = 0.f;
#pragma unroll
    for (int j = 0; j < 8; ++j) {
        const float xv = b2f(v0[j]);
        s1 = fmaf(xv, as_[h * 16 + j], s1);
        s2 = fmaf(xv, ad_[h * 16 + j], s2);
    }
#pragma unroll
    for (int j = 0; j < 8; ++j) {
        const float xv = b2f(v1[j]);
        s1 = fmaf(xv, as_[h * 16 + 8 + j], s1);
        s2 = fmaf(xv, ad_[h * 16 + 8 + j], s2);
    }
    a_src[t] = s1;
    a_dst[t] = s2;
}

// ---------- CSR build ----------
__global__ __launch_bounds__(256)
void hist_kernel(const int* __restrict__ ei, int* __restrict__ deg, int E)
{
    const int i = blockIdx.x * 256 + threadIdx.x;
    if (i < E) atomicAdd(&deg[ei[E + i]], 1);
}

__global__ __launch_bounds__(1024)
void scan_kernel(const int* __restrict__ deg, int* __restrict__ off, int N)
{
    __shared__ int sums[1024];
    const int t = threadIdx.x;
    const int per = (N + 1023) >> 10;
    const int lo = t * per;
    const int hi = (lo + per < N) ? lo + per : N;
    int s = 0;
    for (int i = lo; i < hi; ++i) s += deg[i] + 1;   // +1: self loop
    sums[t] = s;
    __syncthreads();
    for (int o = 1; o < 1024; o <<= 1) {
        int v = (t >= o) ? sums[t - o] : 0;
        __syncthreads();
        sums[t] += v;
        __syncthreads();
    }
    int run = sums[t] - s;   // exclusive
    for (int i = lo; i < hi; ++i) { off[i] = run; run += deg[i] + 1; }
    if (t == 1023) off[N] = sums[1023];
}

__global__ __launch_bounds__(256)
void init_kernel(const int* __restrict__ off, int* __restrict__ cur,
                 int* __restrict__ eid, int N)
{
    const int n = blockIdx.x * 256 + threadIdx.x;
    if (n >= N) return;
    cur[n] = off[n];
    eid[off[n + 1] - 1] = n;   // self-loop slot (edges fill off[n]..off[n+1]-2)
}

__global__ __launch_bounds__(256)
void scat_kernel(const int* __restrict__ ei, int* __restrict__ cur,
                 int* __restrict__ eid, int E)
{
    const int i = blockIdx.x * 256 + threadIdx.x;
    if (i >= E) return;
    const int s = ei[i], d = ei[E + i];
    const int p = atomicAdd(&cur[d], 1);
    eid[p] = s;
}

// ---------- fused gather-aggregate + normalize + residual + LayerNorm ----------
__global__ __launch_bounds__(256)
void edge_ln(const int* __restrict__ off, const int* __restrict__ eid,
             const float* __restrict__ a_src, const float* __restrict__ a_dst,
             const u16* __restrict__ xt, const float* __restrict__ x,
             const float* __restrict__ b_gat, const float* __restrict__ ln_w,
             const float* __restrict__ ln_b, float* __restrict__ hout,
             u16* __restrict__ hb, int N)
{
    const int lane = threadIdx.x & 63;
    const int n = blockIdx.x * 4 + (threadIdx.x >> 6);
    if (n >= N) return;
    const int h0 = lane >> 4, h1 = h0 + 4;
    const float ad0 = a_dst[(size_t)n * 8 + h0];
    const float ad1 = a_dst[(size_t)n * 8 + h1];
    const int beg = off[n], end = off[n + 1];
    float acc0 = 0.f, acc1 = 0.f, z0 = 0.f, z1 = 0.f;
    int s = eid[beg];
    for (int j = beg; j < end; ++j) {
        const int sn = (j + 1 < end) ? eid[j + 1] : 0;   // prefetch next src
        const float as0 = a_src[(size_t)s * 8 + h0];
        const float as1 = a_src[(size_t)s * 8 + h1];
        const float xv0 = b2f(xt[(size_t)s * 128 + lane]);
        const float xv1 = b2f(xt[(size_t)s * 128 + 64 + lane]);
        float e0 = as0 + ad0; e0 = e0 > 0.f ? e0 : 0.2f * e0;
        float e1 = as1 + ad1; e1 = e1 > 0.f ? e1 : 0.2f * e1;
        const float w0 = __expf(e0), w1 = __expf(e1);
        acc0 = fmaf(w0, xv0, acc0); z0 += w0;
        acc1 = fmaf(w1, xv1, acc1); z1 += w1;
        s = sn;
    }
    const size_t base = (size_t)n * 128;
    const float v0 = acc0 / z0 + b_gat[lane] + x[base + lane];
    const float v1 = acc1 / z1 + b_gat[64 + lane] + x[base + 64 + lane];
    float sm = v0 + v1;
#pragma unroll
    for (int o = 32; o; o >>= 1) sm += __shfl_xor(sm, o);
    const float mu = sm * (1.f / 128.f);
    const float d0 = v0 - mu, d1 = v1 - mu;
    float qq = d0 * d0 + d1 * d1;
#pragma unroll
    for (int o = 32; o; o >>= 1) qq += __shfl_xor(qq, o);
    const float rs = rsqrtf(qq * (1.f / 128.f) + 1e-5f);
    const float h0v = d0 * rs * ln_w[lane] + ln_b[lane];
    const float h1v = d1 * rs * ln_w[64 + lane] + ln_b[64 + lane];
    hout[base + lane] = h0v;
    hout[base + 64 + lane] = h1v;
    hb[base + lane] = f2b(h0v);
    hb[base + 64 + lane] = f2b(h1v);
}

extern "C" void kernel_launch(void* const* d_in, const int* in_sizes, int n_in,
                              void* d_out, int out_size, void* d_ws, size_t ws_size,
                              hipStream_t stream)
{
    const float* x     = (const float*)d_in[0];
    const int*   ei    = (const int*)d_in[1];
    const float* mem   = (const float*)d_in[2];
    const float* W     = (const float*)d_in[3];
    // d_in[4] = b_gat
    const float* b_gat = (const float*)d_in[4];
    const float* att_s = (const float*)d_in[5];
    const float* att_d = (const float*)d_in[6];
    const float* ln_w  = (const float*)d_in[7];
    const float* ln_b  = (const float*)d_in[8];
    const float* Wu1   = (const float*)d_in[9];
    const float* bu1   = (const float*)d_in[10];
    const float* Wu2   = (const float*)d_in[11];
    const float* bu2   = (const float*)d_in[12];
    // d_in[13]=Wr, d_in[14]=br : dead code in reference
    const float* Wn    = (const float*)d_in[15];
    const float* bn    = (const float*)d_in[16];

    const int N = in_sizes[0] / 128;
    const int E = in_sizes[1] / 2;
    const size_t nd = (size_t)N * 128;

    char* p = (char*)d_ws;
    auto alloc = [&](size_t bytes) -> char* {
        char* r = p; p += (bytes + 255) & ~(size_t)255; return r;
    };
    // zone A (live through the whole call)
    u16* x_bf   = (u16*)alloc(nd * 2);
    u16* mem_bf = (u16*)alloc(nd * 2);
    u16* h_bf   = (u16*)alloc(nd * 2);
    u16* t2_bf  = (u16*)alloc(nd * 2);
    u16* Wbf    = (u16*)alloc(128 * 128 * 2);
    u16* Wu1t   = (u16*)alloc(256 * 384 * 2);
    u16* Wu2t   = (u16*)alloc(128 * 256 * 2);
    u16* Wnt    = (u16*)alloc(128 * 384 * 2);
    // zone B (dead after edge_ln; u1_bf aliases it afterwards)
    char* zoneB = p;
    float* a_src = (float*)alloc((size_t)N * 8 * 4);
    float* a_dst = (float*)alloc((size_t)N * 8 * 4);
    int*   deg   = (int*)alloc((size_t)N * 4);
    int*   off   = (int*)alloc((size_t)(N + 1) * 4);
    int*   cur   = (int*)alloc((size_t)N * 4);
    int*   eid   = (int*)alloc((size_t)(E + N) * 4);
    u16*   xt_bf = (u16*)alloc(nd * 2);
    u16*   u1_bf = (u16*)zoneB;            // N*256 bf16, overlays zone B

    float* h_out  = (float*)d_out;
    float* um_out = h_out + nd;

    const int mtiles = (N + 63) / 64;

    hipMemsetAsync(deg, 0, (size_t)N * 4, stream);
    conv_xmem<<<(int)((nd / 4 + 255) / 256), 256, 0, stream>>>(x, mem, x_bf, mem_bf, (int)(nd / 4));
    conv_w<<<dim3(384, 4), 256, 0, stream>>>(W, Wu1, Wu2, Wn, Wbf, Wu1t, Wu2t, Wnt);

    // xt = x @ W (bf16)
    mfma_gemm<0><<<dim3(mtiles, 1), 256, 0, stream>>>(
        x_bf, nullptr, nullptr, nullptr, Wbf, nullptr, nullptr, nullptr, nullptr, xt_bf, N);

    attn_kernel<<<(N * 8 + 255) / 256, 256, 0, stream>>>(xt_bf, att_s, att_d, a_src, a_dst, N * 8);

    hist_kernel<<<(E + 255) / 256, 256, 0, stream>>>(ei, deg, E);
    scan_kernel<<<1, 1024, 0, stream>>>(deg, off, N);
    init_kernel<<<(N + 255) / 256, 256, 0, stream>>>(off, cur, eid, N);
    scat_kernel<<<(E + 255) / 256, 256, 0, stream>>>(ei, cur, eid, E);

    edge_ln<<<(N + 3) / 4, 256, 0, stream>>>(off, eid, a_src, a_dst, xt_bf, x,
                                             b_gat, ln_w, ln_b, h_out, h_bf, N);

    // u1 = relu(comb @ Wu1 + bu1)
    mfma_gemm<1><<<dim3(mtiles, 2), 256, 0, stream>>>(
        nullptr, x_bf, mem_bf, h_bf, Wu1t, bu1, nullptr, nullptr, nullptr, u1_bf, N);
    // t2 = u1 @ Wu2 + bu2
    mfma_gemm<2><<<dim3(mtiles, 1), 256, 0, stream>>>(
        u1_bf, nullptr, nullptr, nullptr, Wu2t, bu2, nullptr, nullptr, nullptr, t2_bf, N);
    // um = sigmoid(t2)*mem + (1-sigmoid(t2))*tanh(comb @ Wn + bn)
    mfma_gemm<3><<<dim3(mtiles, 1), 256, 0, stream>>>(
        nullptr, x_bf, mem_bf, h_bf, Wnt, bn, t2_bf, mem, um_out, nullptr, N);
}

// Round 5
// 439.796 us; speedup vs baseline: 1.9405x; 1.1251x over previous
//
#include <hip/hip_runtime.h>
#include <math.h>

typedef unsigned short u16;
typedef short s8v __attribute__((ext_vector_type(8)));
typedef unsigned short us8 __attribute__((ext_vector_type(8)));
typedef unsigned short us4 __attribute__((ext_vector_type(4)));
typedef unsigned short us2 __attribute__((ext_vector_type(2)));
typedef float f4v __attribute__((ext_vector_type(4)));

__device__ __forceinline__ u16 f2b(float f) {
    union { float f; unsigned u; } v; v.f = f;
    unsigned r = (v.u + 0x7FFFu + ((v.u >> 16) & 1u)) >> 16;
    return (u16)r;
}
__device__ __forceinline__ float b2f(u16 b) {
    union { unsigned u; float f; } v; v.u = ((unsigned)b) << 16;
    return v.f;
}

// ---------- convert x, memory to bf16; also zero deg ----------
__global__ __launch_bounds__(256)
void conv_xmem(const float* __restrict__ x, const float* __restrict__ mem,
               u16* __restrict__ xb, u16* __restrict__ mb,
               int* __restrict__ deg, int N, int tot4)
{
    int t = blockIdx.x * 256 + threadIdx.x;
    if (t < N) deg[t] = 0;
    if (t >= tot4) return;
    float4 vx = ((const float4*)x)[t];
    float4 vm = ((const float4*)mem)[t];
    us4 a, b;
    a[0] = f2b(vx.x); a[1] = f2b(vx.y); a[2] = f2b(vx.z); a[3] = f2b(vx.w);
    b[0] = f2b(vm.x); b[1] = f2b(vm.y); b[2] = f2b(vm.z); b[3] = f2b(vm.w);
    ((us4*)xb)[t] = a;
    ((us4*)mb)[t] = b;
}

// ---------- transpose + convert weights via LDS tiles (coalesced writes) ----------
__global__ __launch_bounds__(256)
void conv_w_t(const float* __restrict__ W, const float* __restrict__ Wu1,
              const float* __restrict__ Wu2, const float* __restrict__ Wn,
              u16* __restrict__ Wt, u16* __restrict__ Wu1t,
              u16* __restrict__ Wu2t, u16* __restrict__ Wnt)
{
    __shared__ u16 tl[32][34];
    const int y = blockIdx.y;
    const float* src; u16* dst; int K, Nc;
    if (y == 0)      { src = W;   dst = Wt;   K = 128; Nc = 128; }
    else if (y == 1) { src = Wu1; dst = Wu1t; K = 384; Nc = 256; }
    else if (y == 2) { src = Wu2; dst = Wu2t; K = 256; Nc = 128; }
    else             { src = Wn;  dst = Wnt;  K = 384; Nc = 128; }
    const int tilesK = K >> 5;
    const int bx = blockIdx.x;
    if (bx >= tilesK * (Nc >> 5)) return;
    const int kt = (bx % tilesK) * 32, ct = (bx / tilesK) * 32;
    const int r = threadIdx.x >> 5, c = threadIdx.x & 31;
#pragma unroll
    for (int i = 0; i < 4; ++i)
        tl[r + i * 8][c] = f2b(src[(size_t)(kt + r + i * 8) * Nc + ct + c]);
    __syncthreads();
#pragma unroll
    for (int i = 0; i < 4; ++i)
        dst[(size_t)(ct + r + i * 8) * K + kt + c] = tl[c][r + i * 8];
}

// ---------- bf16 MFMA GEMM ----------
// MODE 0: xt_bf = x_bf @ Wt           (K=128, Nc=128, out bf16)
// MODE 1: u1_bf = relu(comb @ Wu1t+b) (K=384, Nc=256, out bf16)
// MODE 2: t2_bf = u1_bf @ Wu2t + b    (K=256, Nc=128, out bf16)
// MODE 3: um = g*mem+(1-g)*tanh(comb@Wnt+b), g=sigmoid(t2) (out f32)
template<int MODE>
__global__ __launch_bounds__(256)
void mfma_gemm(const u16* __restrict__ Ad, const u16* __restrict__ Xb,
               const u16* __restrict__ Mb, const u16* __restrict__ Hb,
               const u16* __restrict__ Bt, const float* __restrict__ bias,
               const u16* __restrict__ T2b, const float* __restrict__ MemF,
               float* __restrict__ outF, u16* __restrict__ outB, int M)
{
    constexpr int K = (MODE == 0) ? 128 : ((MODE == 2) ? 256 : 384);
    __shared__ __align__(16) u16 As[64][40];
    __shared__ __align__(16) u16 Bs[128][40];
    const int tid = threadIdx.x;
    const int lane = tid & 63;
    const int wid = tid >> 6;
    const int wr = wid >> 1, wc = wid & 1;
    const int row0 = blockIdx.x * 64;
    const int col0 = blockIdx.y * 128;

    f4v acc[2][4];
#pragma unroll
    for (int a = 0; a < 2; ++a)
#pragma unroll
        for (int b = 0; b < 4; ++b)
#pragma unroll
            for (int q = 0; q < 4; ++q) acc[a][b][q] = 0.f;

    const int ar = tid >> 2;
    const int akc = (tid & 3) * 8;
    const int bc = tid >> 1;
    const int bko = (tid & 1) * 16;
    const int lr = lane & 15;
    const int kg = lane >> 4;

    for (int k0 = 0; k0 < K; k0 += 32) {
        {
            int gr = row0 + ar; if (gr > M - 1) gr = M - 1;
            const int gk = k0 + akc;
            const u16* src;
            if (MODE == 1 || MODE == 3) {
                const u16* base = (gk < 128) ? Xb : ((gk < 256) ? Mb : Hb);
                src = base + (size_t)gr * 128 + (gk & 127);
            } else {
                src = Ad + (size_t)gr * K + gk;
            }
            *(us8*)&As[ar][akc] = *(const us8*)src;
        }
        {
            const u16* src = Bt + (size_t)(col0 + bc) * K + k0 + bko;
            *(us8*)&Bs[bc][bko]     = ((const us8*)src)[0];
            *(us8*)&Bs[bc][bko + 8] = ((const us8*)src)[1];
        }
        __syncthreads();
        const s8v a0 = *(const s8v*)&As[wr * 32 + lr][kg * 8];
        const s8v a1 = *(const s8v*)&As[wr * 32 + 16 + lr][kg * 8];
#pragma unroll
        for (int ni = 0; ni < 4; ++ni) {
            const s8v b = *(const s8v*)&Bs[wc * 64 + ni * 16 + lr][kg * 8];
            acc[0][ni] = __builtin_amdgcn_mfma_f32_16x16x32_bf16(a0, b, acc[0][ni], 0, 0, 0);
            acc[1][ni] = __builtin_amdgcn_mfma_f32_16x16x32_bf16(a1, b, acc[1][ni], 0, 0, 0);
        }
        __syncthreads();
    }
#pragma unroll
    for (int mi = 0; mi < 2; ++mi) {
#pragma unroll
        for (int ni = 0; ni < 4; ++ni) {
#pragma unroll
            for (int q = 0; q < 4; ++q) {
                const int row = row0 + wr * 32 + mi * 16 + kg * 4 + q;
                const int col = col0 + wc * 64 + ni * 16 + lr;
                if (row >= M) continue;
                float v = acc[mi][ni][q];
                if (MODE == 0) {
                    outB[(size_t)row * 128 + col] = f2b(v);
                } else if (MODE == 1) {
                    v += bias[col]; v = v > 0.f ? v : 0.f;
                    outB[(size_t)row * 256 + col] = f2b(v);
                } else if (MODE == 2) {
                    v += bias[col];
                    outB[(size_t)row * 128 + col] = f2b(v);
                } else {
                    v = tanhf(v + bias[col]);
                    const float t2 = b2f(T2b[(size_t)row * 128 + col]);
                    const float g = 1.f / (1.f + __expf(-t2));
                    const float mm = MemF[(size_t)row * 128 + col];
                    outF[(size_t)row * 128 + col] = g * mm + (1.f - g) * v;
                }
            }
        }
    }
}

// ---------- attention scores ----------
__global__ __launch_bounds__(256)
void attn_kernel(const u16* __restrict__ xt, const float* __restrict__ as_,
                 const float* __restrict__ ad_, float* __restrict__ a_src,
                 float* __restrict__ a_dst, int tot)
{
    const int t = blockIdx.x * 256 + threadIdx.x;
    if (t >= tot) return;
    const int h = t & 7;
    const size_t n = (size_t)(t >> 3);
    const u16* xp = xt + n * 128 + h * 16;
    const us8 v0 = ((const us8*)xp)[0], v1 = ((const us8*)xp)[1];
    float s1 = 0.f, s2 = 0.f;
#pragma unroll
    for (int j = 0; j < 8; ++j) {
        const float xv = b2f(v0[j]);
        s1 = fmaf(xv, as_[h * 16 + j], s1);
        s2 = fmaf(xv, ad_[h * 16 + j], s2);
    }
#pragma unroll
    for (int j = 0; j < 8; ++j) {
        const float xv = b2f(v1[j]);
        s1 = fmaf(xv, as_[h * 16 + 8 + j], s1);
        s2 = fmaf(xv, ad_[h * 16 + 8 + j], s2);
    }
    a_src[t] = s1;
    a_dst[t] = s2;
}

// ---------- CSR build ----------
__global__ __launch_bounds__(256)
void hist_kernel(const int* __restrict__ ei, int* __restrict__ deg, int E)
{
    const int i = blockIdx.x * 256 + threadIdx.x;
    if (i < E) atomicAdd(&deg[ei[E + i]], 1);
}

// chunked coalesced block scan; also writes cur[] and the self-loop eid slot
__global__ __launch_bounds__(1024)
void scan_kernel(const int* __restrict__ deg, int* __restrict__ off,
                 int* __restrict__ cur, int* __restrict__ eid, int N)
{
    __shared__ int wsum[16];
    __shared__ int carry;
    const int t = threadIdx.x;
    const int lane = t & 63, w = t >> 6;
    if (t == 0) carry = 0;
    __syncthreads();
    for (int base = 0; base < N; base += 1024) {
        const int i = base + t;
        const int v = (i < N) ? deg[i] + 1 : 0;   // +1: self loop
        int s = v;
#pragma unroll
        for (int o = 1; o < 64; o <<= 1) {
            const int u = __shfl_up(s, o);
            if (lane >= o) s += u;
        }
        if (lane == 63) wsum[w] = s;
        __syncthreads();
        if (w == 0) {
            int ws = (lane < 16) ? wsum[lane] : 0;
#pragma unroll
            for (int o = 1; o < 16; o <<= 1) {
                const int u = __shfl_up(ws, o);
                if (lane >= o) ws += u;
            }
            if (lane < 16) wsum[lane] = ws;
        }
        __syncthreads();
        const int excl = carry + (w ? wsum[w - 1] : 0) + s - v;
        if (i < N) {
            off[i] = excl;
            cur[i] = excl;
            eid[excl + v - 1] = i;   // self-loop slot (edges fill excl..excl+v-2)
        }
        __syncthreads();
        if (t == 1023) carry += wsum[15];
        __syncthreads();
    }
    if (t == 0) off[N] = carry;
}

__global__ __launch_bounds__(256)
void scat_kernel(const int* __restrict__ ei, int* __restrict__ cur,
                 int* __restrict__ eid, int E)
{
    const int i = blockIdx.x * 256 + threadIdx.x;
    if (i >= E) return;
    const int s = ei[i], d = ei[E + i];
    const int p = atomicAdd(&cur[d], 1);
    eid[p] = s;
}

// ---------- fused gather-aggregate + normalize + residual + LayerNorm ----------
// lane L handles channels {2L, 2L+1}; both share head h = L>>3.
__global__ __launch_bounds__(256)
void edge_ln(const int* __restrict__ off, const int* __restrict__ eid,
             const float* __restrict__ a_src, const float* __restrict__ a_dst,
             const u16* __restrict__ xt, const float* __restrict__ x,
             const float* __restrict__ b_gat, const float* __restrict__ ln_w,
             const float* __restrict__ ln_b, float* __restrict__ hout,
             u16* __restrict__ hb, int N)
{
    const int L = threadIdx.x & 63;
    const int n = blockIdx.x * 4 + (threadIdx.x >> 6);
    if (n >= N) return;
    const int h = L >> 3;
    const float ad = a_dst[(size_t)n * 8 + h];
    const int beg = off[n], end = off[n + 1];
    const us2* xrow = (const us2*)xt;
    float aE0 = 0.f, aO0 = 0.f, z0 = 0.f;
    float aE1 = 0.f, aO1 = 0.f, z1 = 0.f;
    int j = beg;
    for (; j + 1 < end; j += 2) {
        const int s0 = eid[j], s1 = eid[j + 1];
        const float as0 = a_src[(size_t)s0 * 8 + h];
        const float as1 = a_src[(size_t)s1 * 8 + h];
        const us2 v0 = xrow[(size_t)s0 * 64 + L];
        const us2 v1 = xrow[(size_t)s1 * 64 + L];
        float e0 = as0 + ad; e0 = e0 > 0.f ? e0 : 0.2f * e0;
        float e1 = as1 + ad; e1 = e1 > 0.f ? e1 : 0.2f * e1;
        const float w0 = __expf(e0), w1 = __expf(e1);
        aE0 = fmaf(w0, b2f(v0[0]), aE0); aO0 = fmaf(w0, b2f(v0[1]), aO0); z0 += w0;
        aE1 = fmaf(w1, b2f(v1[0]), aE1); aO1 = fmaf(w1, b2f(v1[1]), aO1); z1 += w1;
    }
    if (j < end) {
        const int s0 = eid[j];
        const float as0 = a_src[(size_t)s0 * 8 + h];
        const us2 v0 = xrow[(size_t)s0 * 64 + L];
        float e0 = as0 + ad; e0 = e0 > 0.f ? e0 : 0.2f * e0;
        const float w0 = __expf(e0);
        aE0 = fmaf(w0, b2f(v0[0]), aE0); aO0 = fmaf(w0, b2f(v0[1]), aO0); z0 += w0;
    }
    const float zi = 1.f / (z0 + z1);
    const size_t base = (size_t)n * 128;
    const float2 xv = ((const float2*)(x + base))[L];
    const float2 bg = ((const float2*)b_gat)[L];
    const float u0 = (aE0 + aE1) * zi + bg.x + xv.x;
    const float u1 = (aO0 + aO1) * zi + bg.y + xv.y;
    float sm = u0 + u1;
#pragma unroll
    for (int o = 32; o; o >>= 1) sm += __shfl_xor(sm, o);
    const float mu = sm * (1.f / 128.f);
    const float d0 = u0 - mu, d1 = u1 - mu;
    float qq = d0 * d0 + d1 * d1;
#pragma unroll
    for (int o = 32; o; o >>= 1) qq += __shfl_xor(qq, o);
    const float rs = rsqrtf(qq * (1.f / 128.f) + 1e-5f);
    const float2 lw = ((const float2*)ln_w)[L];
    const float2 lb = ((const float2*)ln_b)[L];
    const float o0 = d0 * rs * lw.x + lb.x;
    const float o1 = d1 * rs * lw.y + lb.y;
    float2 of; of.x = o0; of.y = o1;
    ((float2*)(hout + base))[L] = of;
    us2 ob; ob[0] = f2b(o0); ob[1] = f2b(o1);
    ((us2*)(hb + base))[L] = ob;
}

extern "C" void kernel_launch(void* const* d_in, const int* in_sizes, int n_in,
                              void* d_out, int out_size, void* d_ws, size_t ws_size,
                              hipStream_t stream)
{
    const float* x     = (const float*)d_in[0];
    const int*   ei    = (const int*)d_in[1];
    const float* mem   = (const float*)d_in[2];
    const float* W     = (const float*)d_in[3];
    const float* b_gat = (const float*)d_in[4];
    const float* att_s = (const float*)d_in[5];
    const float* att_d = (const float*)d_in[6];
    const float* ln_w  = (const float*)d_in[7];
    const float* ln_b  = (const float*)d_in[8];
    const float* Wu1   = (const float*)d_in[9];
    const float* bu1   = (const float*)d_in[10];
    const float* Wu2   = (const float*)d_in[11];
    const float* bu2   = (const float*)d_in[12];
    // d_in[13]=Wr, d_in[14]=br : dead code in reference
    const float* Wn    = (const float*)d_in[15];
    const float* bn    = (const float*)d_in[16];

    const int N = in_sizes[0] / 128;
    const int E = in_sizes[1] / 2;
    const size_t nd = (size_t)N * 128;

    char* p = (char*)d_ws;
    auto alloc = [&](size_t bytes) -> char* {
        char* r = p; p += (bytes + 255) & ~(size_t)255; return r;
    };
    // zone A (live through the whole call)
    u16* x_bf   = (u16*)alloc(nd * 2);
    u16* mem_bf = (u16*)alloc(nd * 2);
    u16* h_bf   = (u16*)alloc(nd * 2);
    u16* t2_bf  = (u16*)alloc(nd * 2);
    u16* Wbf    = (u16*)alloc(128 * 128 * 2);
    u16* Wu1t   = (u16*)alloc(256 * 384 * 2);
    u16* Wu2t   = (u16*)alloc(128 * 256 * 2);
    u16* Wnt    = (u16*)alloc(128 * 384 * 2);
    // zone B (dead after edge_ln; u1_bf overlays it afterwards)
    char* zoneB = p;
    float* a_src = (float*)alloc((size_t)N * 8 * 4);
    float* a_dst = (float*)alloc((size_t)N * 8 * 4);
    int*   deg   = (int*)alloc((size_t)N * 4);
    int*   off   = (int*)alloc((size_t)(N + 1) * 4);
    int*   cur   = (int*)alloc((size_t)N * 4);
    int*   eid   = (int*)alloc((size_t)(E + N) * 4);
    u16*   xt_bf = (u16*)alloc(nd * 2);
    u16*   u1_bf = (u16*)zoneB;            // N*256 bf16 overlay

    float* h_out  = (float*)d_out;
    float* um_out = h_out + nd;

    const int mtiles = (N + 63) / 64;

    conv_xmem<<<(int)((nd / 4 + 255) / 256), 256, 0, stream>>>(
        x, mem, x_bf, mem_bf, deg, N, (int)(nd / 4));
    conv_w_t<<<dim3(96, 4), 256, 0, stream>>>(W, Wu1, Wu2, Wn, Wbf, Wu1t, Wu2t, Wnt);

    // xt = x @ W (bf16)
    mfma_gemm<0><<<dim3(mtiles, 1), 256, 0, stream>>>(
        x_bf, nullptr, nullptr, nullptr, Wbf, nullptr, nullptr, nullptr, nullptr, xt_bf, N);

    attn_kernel<<<(N * 8 + 255) / 256, 256, 0, stream>>>(xt_bf, att_s, att_d, a_src, a_dst, N * 8);

    hist_kernel<<<(E + 255) / 256, 256, 0, stream>>>(ei, deg, E);
    scan_kernel<<<1, 1024, 0, stream>>>(deg, off, cur, eid, N);
    scat_kernel<<<(E + 255) / 256, 256, 0, stream>>>(ei, cur, eid, E);

    edge_ln<<<(N + 3) / 4, 256, 0, stream>>>(off, eid, a_src, a_dst, xt_bf, x,
                                             b_gat, ln_w, ln_b, h_out, h_bf, N);

    // u1 = relu(comb @ Wu1 + bu1)
    mfma_gemm<1><<<dim3(mtiles, 2), 256, 0, stream>>>(
        nullptr, x_bf, mem_bf, h_bf, Wu1t, bu1, nullptr, nullptr, nullptr, u1_bf, N);
    // t2 = u1 @ Wu2 + bu2
    mfma_gemm<2><<<dim3(mtiles, 1), 256, 0, stream>>>(
        u1_bf, nullptr, nullptr, nullptr, Wu2t, bu2, nullptr, nullptr, nullptr, t2_bf, N);
    // um = sigmoid(t2)*mem + (1-sigmoid(t2))*tanh(comb @ Wn + bn)
    mfma_gemm<3><<<dim3(mtiles, 1), 256, 0, stream>>>(
        nullptr, x_bf, mem_bf, h_bf, Wnt, bn, t2_bf, mem, um_out, nullptr, N);
}

// Round 8
// 412.242 us; speedup vs baseline: 2.0702x; 1.0668x over previous
//
#include <hip/hip_runtime.h>
#include <math.h>

typedef unsigned short u16;
typedef short s8v __attribute__((ext_vector_type(8)));
typedef unsigned short us8 __attribute__((ext_vector_type(8)));
typedef unsigned short us4 __attribute__((ext_vector_type(4)));
typedef unsigned short us2 __attribute__((ext_vector_type(2)));
typedef float f4v __attribute__((ext_vector_type(4)));

__device__ __forceinline__ u16 f2b(float f) {
    union { float f; unsigned u; } v; v.f = f;
    unsigned r = (v.u + 0x7FFFu + ((v.u >> 16) & 1u)) >> 16;
    return (u16)r;
}
__device__ __forceinline__ float b2f(u16 b) {
    union { unsigned u; float f; } v; v.u = ((unsigned)b) << 16;
    return v.f;
}

// ---------- convert x, memory to bf16; also zero deg ----------
__global__ __launch_bounds__(256)
void conv_xmem(const float* __restrict__ x, const float* __restrict__ mem,
               u16* __restrict__ xb, u16* __restrict__ mb,
               int* __restrict__ deg, int N, int tot4)
{
    int t = blockIdx.x * 256 + threadIdx.x;
    if (t < N) deg[t] = 0;
    if (t >= tot4) return;
    float4 vx = ((const float4*)x)[t];
    float4 vm = ((const float4*)mem)[t];
    us4 a, b;
    a[0] = f2b(vx.x); a[1] = f2b(vx.y); a[2] = f2b(vx.z); a[3] = f2b(vx.w);
    b[0] = f2b(vm.x); b[1] = f2b(vm.y); b[2] = f2b(vm.z); b[3] = f2b(vm.w);
    ((us4*)xb)[t] = a;
    ((us4*)mb)[t] = b;
}

// ---------- transpose + convert weights via LDS tiles ----------
__global__ __launch_bounds__(256)
void conv_w_t(const float* __restrict__ W, const float* __restrict__ Wu1,
              const float* __restrict__ Wu2, const float* __restrict__ Wn,
              u16* __restrict__ Wt, u16* __restrict__ Wu1t,
              u16* __restrict__ Wu2t, u16* __restrict__ Wnt)
{
    __shared__ u16 tl[32][34];
    const int y = blockIdx.y;
    const float* src; u16* dst; int K, Nc;
    if (y == 0)      { src = W;   dst = Wt;   K = 128; Nc = 128; }
    else if (y == 1) { src = Wu1; dst = Wu1t; K = 384; Nc = 256; }
    else if (y == 2) { src = Wu2; dst = Wu2t; K = 256; Nc = 128; }
    else             { src = Wn;  dst = Wnt;  K = 384; Nc = 128; }
    const int tilesK = K >> 5;
    const int bx = blockIdx.x;
    if (bx >= tilesK * (Nc >> 5)) return;
    const int kt = (bx % tilesK) * 32, ct = (bx / tilesK) * 32;
    const int r = threadIdx.x >> 5, c = threadIdx.x & 31;
#pragma unroll
    for (int i = 0; i < 4; ++i)
        tl[r + i * 8][c] = f2b(src[(size_t)(kt + r + i * 8) * Nc + ct + c]);
    __syncthreads();
#pragma unroll
    for (int i = 0; i < 4; ++i)
        dst[(size_t)(ct + r + i * 8) * K + kt + c] = tl[c][r + i * 8];
}

// ---------- bf16 MFMA GEMM ----------
// MODE 0: xt_bf = x_bf @ Wt   (K=128, NCOL=128, out bf16, stride 128)
// MODE 1: u1_bf = relu(comb @ Wu1t+b) (K=384, NCOL=256, out bf16, stride 256)
template<int MODE, int NCOL>
__global__ __launch_bounds__(256)
void mfma_gemm(const u16* __restrict__ Ad, const u16* __restrict__ Xb,
               const u16* __restrict__ Mb, const u16* __restrict__ Hb,
               const u16* __restrict__ Bt, const float* __restrict__ bias,
               u16* __restrict__ outB, int M)
{
    constexpr int K = (MODE == 0) ? 128 : 384;
    constexpr int NI = NCOL / 32;       // per-wave 16-col groups
    __shared__ __align__(16) u16 As[64][40];
    __shared__ __align__(16) u16 Bs[NCOL][40];
    const int tid = threadIdx.x;
    const int lane = tid & 63;
    const int wid = tid >> 6;
    const int wr = wid >> 1, wc = wid & 1;
    const int row0 = blockIdx.x * 64;
    const int col0 = blockIdx.y * NCOL;

    f4v acc[2][NI];
#pragma unroll
    for (int a = 0; a < 2; ++a)
#pragma unroll
        for (int b = 0; b < NI; ++b)
#pragma unroll
            for (int q = 0; q < 4; ++q) acc[a][b][q] = 0.f;

    const int ar = tid >> 2;
    const int akc = (tid & 3) * 8;
    const int lr = lane & 15;
    const int kg = lane >> 4;

    for (int k0 = 0; k0 < K; k0 += 32) {
        {
            int gr = row0 + ar; if (gr > M - 1) gr = M - 1;
            const int gk = k0 + akc;
            const u16* src;
            if (MODE == 1) {
                const u16* base = (gk < 128) ? Xb : ((gk < 256) ? Mb : Hb);
                src = base + (size_t)gr * 128 + (gk & 127);
            } else {
                src = Ad + (size_t)gr * K + gk;
            }
            *(us8*)&As[ar][akc] = *(const us8*)src;
        }
        if (NCOL == 128) {
            const int bc = tid >> 1, bko = (tid & 1) * 16;
            const u16* src = Bt + (size_t)(col0 + bc) * K + k0 + bko;
            *(us8*)&Bs[bc][bko]     = ((const us8*)src)[0];
            *(us8*)&Bs[bc][bko + 8] = ((const us8*)src)[1];
        } else {
            const u16* src = Bt + (size_t)(col0 + tid) * K + k0;
#pragma unroll
            for (int j = 0; j < 4; ++j)
                *(us8*)&Bs[tid][j * 8] = ((const us8*)src)[j];
        }
        __syncthreads();
        const s8v a0 = *(const s8v*)&As[wr * 32 + lr][kg * 8];
        const s8v a1 = *(const s8v*)&As[wr * 32 + 16 + lr][kg * 8];
#pragma unroll
        for (int ni = 0; ni < NI; ++ni) {
            const s8v b = *(const s8v*)&Bs[wc * (NCOL / 2) + ni * 16 + lr][kg * 8];
            acc[0][ni] = __builtin_amdgcn_mfma_f32_16x16x32_bf16(a0, b, acc[0][ni], 0, 0, 0);
            acc[1][ni] = __builtin_amdgcn_mfma_f32_16x16x32_bf16(a1, b, acc[1][ni], 0, 0, 0);
        }
        __syncthreads();
    }
#pragma unroll
    for (int mi = 0; mi < 2; ++mi) {
#pragma unroll
        for (int ni = 0; ni < NI; ++ni) {
#pragma unroll
            for (int q = 0; q < 4; ++q) {
                const int row = row0 + wr * 32 + mi * 16 + kg * 4 + q;
                const int col = col0 + wc * (NCOL / 2) + ni * 16 + lr;
                if (row >= M) continue;
                float v = acc[mi][ni][q];
                if (MODE == 0) {
                    outB[(size_t)row * 128 + col] = f2b(v);
                } else {
                    v += bias[col]; v = v > 0.f ? v : 0.f;
                    outB[(size_t)row * 256 + col] = f2b(v);
                }
            }
        }
    }
}

// ---------- fused GEMM 2+3: t2 = u1@Wu2+bu2 (K=256); nm = comb@Wnt+bn (K=384)
//            out = sigmoid(t2)*mem + (1-sigmoid(t2))*tanh(nm)
__global__ __launch_bounds__(256)
void mfma_gemm23(const u16* __restrict__ U1, const u16* __restrict__ Xb,
                 const u16* __restrict__ Mb, const u16* __restrict__ Hb,
                 const u16* __restrict__ Wu2t, const u16* __restrict__ Wnt,
                 const float* __restrict__ bu2, const float* __restrict__ bn,
                 const float* __restrict__ MemF, float* __restrict__ outF, int M)
{
    __shared__ __align__(16) u16 As[64][40];
    __shared__ __align__(16) u16 Bs[128][40];
    const int tid = threadIdx.x;
    const int lane = tid & 63;
    const int wid = tid >> 6;
    const int wr = wid >> 1, wc = wid & 1;
    const int row0 = blockIdx.x * 64;
    const int ar = tid >> 2;
    const int akc = (tid & 3) * 8;
    const int bc = tid >> 1, bko = (tid & 1) * 16;
    const int lr = lane & 15;
    const int kg = lane >> 4;

    f4v acc[2][4];
    float gg[2][4][4];

    // ---- phase 1: t2 over u1 (K=256) ----
#pragma unroll
    for (int a = 0; a < 2; ++a)
#pragma unroll
        for (int b = 0; b < 4; ++b)
#pragma unroll
            for (int q = 0; q < 4; ++q) acc[a][b][q] = 0.f;
    for (int k0 = 0; k0 < 256; k0 += 32) {
        {
            int gr = row0 + ar; if (gr > M - 1) gr = M - 1;
            *(us8*)&As[ar][akc] = *(const us8*)(U1 + (size_t)gr * 256 + k0 + akc);
        }
        {
            const u16* src = Wu2t + (size_t)bc * 256 + k0 + bko;
            *(us8*)&Bs[bc][bko]     = ((const us8*)src)[0];
            *(us8*)&Bs[bc][bko + 8] = ((const us8*)src)[1];
        }
        __syncthreads();
        const s8v a0 = *(const s8v*)&As[wr * 32 + lr][kg * 8];
        const s8v a1 = *(const s8v*)&As[wr * 32 + 16 + lr][kg * 8];
#pragma unroll
        for (int ni = 0; ni < 4; ++ni) {
            const s8v b = *(const s8v*)&Bs[wc * 64 + ni * 16 + lr][kg * 8];
            acc[0][ni] = __builtin_amdgcn_mfma_f32_16x16x32_bf16(a0, b, acc[0][ni], 0, 0, 0);
            acc[1][ni] = __builtin_amdgcn_mfma_f32_16x16x32_bf16(a1, b, acc[1][ni], 0, 0, 0);
        }
        __syncthreads();
    }
#pragma unroll
    for (int mi = 0; mi < 2; ++mi)
#pragma unroll
        for (int ni = 0; ni < 4; ++ni)
#pragma unroll
            for (int q = 0; q < 4; ++q) {
                const int col = wc * 64 + ni * 16 + lr;
                const float t2 = acc[mi][ni][q] + bu2[col];
                gg[mi][ni][q] = 1.f / (1.f + __expf(-t2));
            }

    // ---- phase 2: nm over comb (K=384) ----
#pragma unroll
    for (int a = 0; a < 2; ++a)
#pragma unroll
        for (int b = 0; b < 4; ++b)
#pragma unroll
            for (int q = 0; q < 4; ++q) acc[a][b][q] = 0.f;
    for (int k0 = 0; k0 < 384; k0 += 32) {
        {
            int gr = row0 + ar; if (gr > M - 1) gr = M - 1;
            const int gk = k0 + akc;
            const u16* base = (gk < 128) ? Xb : ((gk < 256) ? Mb : Hb);
            *(us8*)&As[ar][akc] = *(const us8*)(base + (size_t)gr * 128 + (gk & 127));
        }
        {
            const u16* src = Wnt + (size_t)bc * 384 + k0 + bko;
            *(us8*)&Bs[bc][bko]     = ((const us8*)src)[0];
            *(us8*)&Bs[bc][bko + 8] = ((const us8*)src)[1];
        }
        __syncthreads();
        const s8v a0 = *(const s8v*)&As[wr * 32 + lr][kg * 8];
        const s8v a1 = *(const s8v*)&As[wr * 32 + 16 + lr][kg * 8];
#pragma unroll
        for (int ni = 0; ni < 4; ++ni) {
            const s8v b = *(const s8v*)&Bs[wc * 64 + ni * 16 + lr][kg * 8];
            acc[0][ni] = __builtin_amdgcn_mfma_f32_16x16x32_bf16(a0, b, acc[0][ni], 0, 0, 0);
            acc[1][ni] = __builtin_amdgcn_mfma_f32_16x16x32_bf16(a1, b, acc[1][ni], 0, 0, 0);
        }
        __syncthreads();
    }
#pragma unroll
    for (int mi = 0; mi < 2; ++mi)
#pragma unroll
        for (int ni = 0; ni < 4; ++ni)
#pragma unroll
            for (int q = 0; q < 4; ++q) {
                const int row = row0 + wr * 32 + mi * 16 + kg * 4 + q;
                const int col = wc * 64 + ni * 16 + lr;
                if (row >= M) continue;
                const float nm = tanhf(acc[mi][ni][q] + bn[col]);
                const float g = gg[mi][ni][q];
                const float mm = MemF[(size_t)row * 128 + col];
                outF[(size_t)row * 128 + col] = g * mm + (1.f - g) * nm;
            }
}

// ---------- attention scores ----------
__global__ __launch_bounds__(256)
void attn_kernel(const u16* __restrict__ xt, const float* __restrict__ as_,
                 const float* __restrict__ ad_, float* __restrict__ a_src,
                 float* __restrict__ a_dst, int tot)
{
    const int t = blockIdx.x * 256 + threadIdx.x;
    if (t >= tot) return;
    const int h = t & 7;
    const size_t n = (size_t)(t >> 3);
    const u16* xp = xt + n * 128 + h * 16;
    const us8 v0 = ((const us8*)xp)[0], v1 = ((const us8*)xp)[1];
    float s1 = 0.f, s2 = 0.f;
#pragma unroll
    for (int j = 0; j < 8; ++j) {
        const float xv = b2f(v0[j]);
        s1 = fmaf(xv, as_[h * 16 + j], s1);
        s2 = fmaf(xv, ad_[h * 16 + j], s2);
    }
#pragma unroll
    for (int j = 0; j < 8; ++j) {
        const float xv = b2f(v1[j]);
        s1 = fmaf(xv, as_[h * 16 + 8 + j], s1);
        s2 = fmaf(xv, ad_[h * 16 + 8 + j], s2);
    }
    a_src[t] = s1;
    a_dst[t] = s2;
}

// ---------- CSR build ----------
__global__ __launch_bounds__(256)
void hist_kernel(const int* __restrict__ ei, int* __restrict__ deg, int E)
{
    const int i = blockIdx.x * 256 + threadIdx.x;
    if (i < E) atomicAdd(&deg[ei[E + i]], 1);
}

// int4-vectorized chunked block scan; writes off, cur, self-loop eid slots
__global__ __launch_bounds__(1024)
void scan_kernel(const int* __restrict__ deg, int* __restrict__ off,
                 int* __restrict__ cur, int* __restrict__ eid, int N)
{
    __shared__ int wsum[16];
    __shared__ int carry;
    const int t = threadIdx.x;
    const int lane = t & 63, w = t >> 6;
    if (t == 0) carry = 0;
    __syncthreads();
    const int N4 = (N + 3) >> 2;
    for (int base = 0; base < N4; base += 1024) {
        const int g = base + t;
        int c0 = 0, c1 = 0, c2 = 0, c3 = 0;
        if (g < N4) {
            const int i0 = g * 4;
            if (i0 + 3 < N) {
                const int4 v = ((const int4*)deg)[g];
                c0 = v.x + 1; c1 = v.y + 1; c2 = v.z + 1; c3 = v.w + 1;
            } else {
                c0 = (i0 < N) ? deg[i0] + 1 : 0;
                c1 = (i0 + 1 < N) ? deg[i0 + 1] + 1 : 0;
                c2 = (i0 + 2 < N) ? deg[i0 + 2] + 1 : 0;
                c3 = (i0 + 3 < N) ? deg[i0 + 3] + 1 : 0;
            }
        }
        const int s = c0 + c1 + c2 + c3;
        int ps = s;
#pragma unroll
        for (int o = 1; o < 64; o <<= 1) {
            const int u = __shfl_up(ps, o);
            if (lane >= o) ps += u;
        }
        if (lane == 63) wsum[w] = ps;
        __syncthreads();
        if (w == 0) {
            int ws = (lane < 16) ? wsum[lane] : 0;
#pragma unroll
            for (int o = 1; o < 16; o <<= 1) {
                const int u = __shfl_up(ws, o);
                if (lane >= o) ws += u;
            }
            if (lane < 16) wsum[lane] = ws;
        }
        __syncthreads();
        const int excl = carry + (w ? wsum[w - 1] : 0) + ps - s;
        if (g < N4) {
            const int i0 = g * 4;
            const int o0 = excl, o1 = o0 + c0, o2 = o1 + c1, o3 = o2 + c2;
            if (i0 + 3 < N) {
                int4 ov; ov.x = o0; ov.y = o1; ov.z = o2; ov.w = o3;
                ((int4*)off)[g] = ov;
                ((int4*)cur)[g] = ov;
                eid[o0 + c0 - 1] = i0;
                eid[o1 + c1 - 1] = i0 + 1;
                eid[o2 + c2 - 1] = i0 + 2;
                eid[o3 + c3 - 1] = i0 + 3;
            } else {
                if (i0 < N)     { off[i0] = o0;     cur[i0] = o0;     eid[o0 + c0 - 1] = i0; }
                if (i0 + 1 < N) { off[i0 + 1] = o1; cur[i0 + 1] = o1; eid[o1 + c1 - 1] = i0 + 1; }
                if (i0 + 2 < N) { off[i0 + 2] = o2; cur[i0 + 2] = o2; eid[o2 + c2 - 1] = i0 + 2; }
                if (i0 + 3 < N) { off[i0 + 3] = o3; cur[i0 + 3] = o3; eid[o3 + c3 - 1] = i0 + 3; }
            }
        }
        __syncthreads();
        if (t == 1023) carry += wsum[15];
        __syncthreads();
    }
    if (t == 0) off[N] = carry;
}

__global__ __launch_bounds__(256)
void scat_kernel(const int* __restrict__ ei, int* __restrict__ cur,
                 int* __restrict__ eid, int E)
{
    const int i = blockIdx.x * 256 + threadIdx.x;
    if (i >= E) return;
    const int s = ei[i], d = ei[E + i];
    const int p = atomicAdd(&cur[d], 1);
    eid[p] = s;
}

// ---------- fused gather-aggregate + normalize + residual + LayerNorm ----------
// lane L: channels {2L,2L+1} (head hc=L>>3). Weight duty: edge (L>>3), head (L&7)
// -> the 64 distinct (edge,head) weights per 8-edge chunk are each computed ONCE,
//    then distributed by shuffles (8x fewer exp/leaky/a_src-gather than per-lane).
__global__ __launch_bounds__(256)
void edge_ln(const int* __restrict__ off, const int* __restrict__ eid,
             const float* __restrict__ a_src, const float* __restrict__ a_dst,
             const u16* __restrict__ xt, const float* __restrict__ x,
             const float* __restrict__ b_gat, const float* __restrict__ ln_w,
             const float* __restrict__ ln_b, float* __restrict__ hout,
             u16* __restrict__ hb, int N)
{
    const int L = threadIdx.x & 63;
    const int n = blockIdx.x * 4 + (threadIdx.x >> 6);
    if (n >= N) return;
    const int hc = L >> 3;          // head of my channels
    const int hw = L & 7;           // weight-duty head
    const int jw = L >> 3;          // weight-duty edge slot
    const float adw = a_dst[(size_t)n * 8 + hw];
    const int beg = off[n], end = off[n + 1];
    const us2* xrow = (const us2*)xt;
    float aE0 = 0.f, aO0 = 0.f, z0 = 0.f;
    float aE1 = 0.f, aO1 = 0.f, z1 = 0.f;
    int j = beg;
    const int nfull = (end - beg) >> 3;
    for (int c8 = 0; c8 < nfull; ++c8, j += 8) {
        const int eload = eid[j + jw];
        const float as = a_src[(size_t)eload * 8 + hw];
        float e = as + adw;
        e = fmaxf(e, 0.f) + 0.2f * fminf(e, 0.f);
        const float wl = __expf(e);
#pragma unroll
        for (int jj = 0; jj < 8; ++jj) {
            const int sj = __shfl(eload, jj << 3);
            const float wj = __shfl(wl, (jj << 3) | hc);
            const us2 v = xrow[(size_t)sj * 64 + L];
            if (jj & 1) { aE1 = fmaf(wj, b2f(v[0]), aE1); aO1 = fmaf(wj, b2f(v[1]), aO1); z1 += wj; }
            else        { aE0 = fmaf(wj, b2f(v[0]), aE0); aO0 = fmaf(wj, b2f(v[1]), aO0); z0 += wj; }
        }
    }
    const int rem = end - j;
    if (rem > 0) {
        const int idx = j + jw;
        const int eload = eid[idx < end ? idx : end - 1];
        const float as = a_src[(size_t)eload * 8 + hw];
        float e = as + adw;
        e = fmaxf(e, 0.f) + 0.2f * fminf(e, 0.f);
        const float wl = (idx < end) ? __expf(e) : 0.f;
        for (int jj = 0; jj < rem; ++jj) {
            const int sj = __shfl(eload, jj << 3);
            const float wj = __shfl(wl, (jj << 3) | hc);
            const us2 v = xrow[(size_t)sj * 64 + L];
            if (jj & 1) { aE1 = fmaf(wj, b2f(v[0]), aE1); aO1 = fmaf(wj, b2f(v[1]), aO1); z1 += wj; }
            else        { aE0 = fmaf(wj, b2f(v[0]), aE0); aO0 = fmaf(wj, b2f(v[1]), aO0); z0 += wj; }
        }
    }
    const float zi = 1.f / (z0 + z1);
    const size_t base = (size_t)n * 128;
    const float2 xv = ((const float2*)(x + base))[L];
    const float2 bg = ((const float2*)b_gat)[L];
    const float u0 = (aE0 + aE1) * zi + bg.x + xv.x;
    const float u1 = (aO0 + aO1) * zi + bg.y + xv.y;
    float sm = u0 + u1;
#pragma unroll
    for (int o = 32; o; o >>= 1) sm += __shfl_xor(sm, o);
    const float mu = sm * (1.f / 128.f);
    const float d0 = u0 - mu, d1 = u1 - mu;
    float qq = d0 * d0 + d1 * d1;
#pragma unroll
    for (int o = 32; o; o >>= 1) qq += __shfl_xor(qq, o);
    const float rs = rsqrtf(qq * (1.f / 128.f) + 1e-5f);
    const float2 lw = ((const float2*)ln_w)[L];
    const float2 lb = ((const float2*)ln_b)[L];
    const float o0 = d0 * rs * lw.x + lb.x;
    const float o1 = d1 * rs * lw.y + lb.y;
    float2 of; of.x = o0; of.y = o1;
    ((float2*)(hout + base))[L] = of;
    us2 ob; ob[0] = f2b(o0); ob[1] = f2b(o1);
    ((us2*)(hb + base))[L] = ob;
}

extern "C" void kernel_launch(void* const* d_in, const int* in_sizes, int n_in,
                              void* d_out, int out_size, void* d_ws, size_t ws_size,
                              hipStream_t stream)
{
    const float* x     = (const float*)d_in[0];
    const int*   ei    = (const int*)d_in[1];
    const float* mem   = (const float*)d_in[2];
    const float* W     = (const float*)d_in[3];
    const float* b_gat = (const float*)d_in[4];
    const float* att_s = (const float*)d_in[5];
    const float* att_d = (const float*)d_in[6];
    const float* ln_w  = (const float*)d_in[7];
    const float* ln_b  = (const float*)d_in[8];
    const float* Wu1   = (const float*)d_in[9];
    const float* bu1   = (const float*)d_in[10];
    const float* Wu2   = (const float*)d_in[11];
    const float* bu2   = (const float*)d_in[12];
    // d_in[13]=Wr, d_in[14]=br : dead code in reference
    const float* Wn    = (const float*)d_in[15];
    const float* bn    = (const float*)d_in[16];

    const int N = in_sizes[0] / 128;
    const int E = in_sizes[1] / 2;
    const size_t nd = (size_t)N * 128;

    char* p = (char*)d_ws;
    auto alloc = [&](size_t bytes) -> char* {
        char* r = p; p += (bytes + 255) & ~(size_t)255; return r;
    };
    // zone A (live through the whole call)
    u16* x_bf   = (u16*)alloc(nd * 2);
    u16* mem_bf = (u16*)alloc(nd * 2);
    u16* h_bf   = (u16*)alloc(nd * 2);
    u16* Wbf    = (u16*)alloc(128 * 128 * 2);
    u16* Wu1t   = (u16*)alloc(256 * 384 * 2);
    u16* Wu2t   = (u16*)alloc(128 * 256 * 2);
    u16* Wnt    = (u16*)alloc(128 * 384 * 2);
    // zone B (dead after edge_ln; u1_bf overlays it afterwards)
    char* zoneB = p;
    float* a_src = (float*)alloc((size_t)N * 8 * 4);
    float* a_dst = (float*)alloc((size_t)N * 8 * 4);
    int*   deg   = (int*)alloc((size_t)N * 4);
    int*   off   = (int*)alloc((size_t)(N + 1) * 4);
    int*   cur   = (int*)alloc((size_t)N * 4);
    int*   eid   = (int*)alloc((size_t)(E + N) * 4);
    u16*   xt_bf = (u16*)alloc(nd * 2);
    u16*   u1_bf = (u16*)zoneB;            // N*256 bf16 overlay

    float* h_out  = (float*)d_out;
    float* um_out = h_out + nd;

    const int mtiles = (N + 63) / 64;

    conv_xmem<<<(int)((nd / 4 + 255) / 256), 256, 0, stream>>>(
        x, mem, x_bf, mem_bf, deg, N, (int)(nd / 4));
    conv_w_t<<<dim3(96, 4), 256, 0, stream>>>(W, Wu1, Wu2, Wn, Wbf, Wu1t, Wu2t, Wnt);

    // xt = x @ W (bf16)
    mfma_gemm<0, 128><<<dim3(mtiles, 1), 256, 0, stream>>>(
        x_bf, nullptr, nullptr, nullptr, Wbf, nullptr, xt_bf, N);

    attn_kernel<<<(N * 8 + 255) / 256, 256, 0, stream>>>(xt_bf, att_s, att_d, a_src, a_dst, N * 8);

    hist_kernel<<<(E + 255) / 256, 256, 0, stream>>>(ei, deg, E);
    scan_kernel<<<1, 1024, 0, stream>>>(deg, off, cur, eid, N);
    scat_kernel<<<(E + 255) / 256, 256, 0, stream>>>(ei, cur, eid, E);

    edge_ln<<<(N + 3) / 4, 256, 0, stream>>>(off, eid, a_src, a_dst, xt_bf, x,
                                             b_gat, ln_w, ln_b, h_out, h_bf, N);

    // u1 = relu(comb @ Wu1 + bu1)  (single 256-col block column: A read once)
    mfma_gemm<1, 256><<<dim3(mtiles, 1), 256, 0, stream>>>(
        nullptr, x_bf, mem_bf, h_bf, Wu1t, bu1, u1_bf, N);

    // fused: t2 = u1@Wu2+bu2 ; um = sigmoid(t2)*mem + (1-sigmoid(t2))*tanh(comb@Wn+bn)
    mfma_gemm23<<<dim3(mtiles, 1), 256, 0, stream>>>(
        u1_bf, x_bf, mem_bf, h_bf, Wu2t, Wnt, bu2, bn, mem, um_out, N);
}